// Round 4
// baseline (139.857 us; speedup 1.0000x reference)
//
#include <hip/hip_runtime.h>
#include <hip/hip_fp16.h>

typedef _Float16 half8 __attribute__((ext_vector_type(8)));
typedef _Float16 half4v __attribute__((ext_vector_type(4)));
typedef __attribute__((ext_vector_type(4))) float f32x4;

#define OUT_ELEMS 8388608

// ws layout (bytes):
// 0      counts int[1024]        (zeroed by prep block 0)
// 4096   loss   float            (zeroed by prep)
// 8192   sq     float[1024]
// 16384  chs    ushort[1024*256] (fp16 of 1024*cb, TILED+SWIZZLED, see below)
//
// chs layout (ushorts): [stage s:16][group g:4][chunk:512][8]
//   code = g*256 + s*16 + m; logical 16B chunk j (d = j*8, j=0..31) of code m
//   is stored at chunk position  m*32 + (j ^ (m&7))   (XOR swizzle).
// vq stages each 8KB wave-slice LINEARLY into LDS via global_load_lds
// (linear dest required) and reads B-frags with the same XOR -> conflict-free.

// ---- prep: zero accumulators + codebook -> fp16*1024 (tiled/swizzled) + ||c||^2 ----
__global__ __launch_bounds__(256) void prep_kernel(const float* __restrict__ cb,
        unsigned short* __restrict__ chs, float* __restrict__ sq,
        int* __restrict__ counts, float* __restrict__ loss) {
    const int t = threadIdx.x;
    if (blockIdx.x == 0) {
        ((int4*)counts)[t] = make_int4(0, 0, 0, 0);
        if (t == 0) *loss = 0.f;
    }
    const int row = blockIdx.x * 16 + (t >> 4);   // code index 0..1023
    const int d0 = (t & 15) * 16;
    const float* src = cb + row * 256 + d0;
    half8 h0, h1;
    float s = 0.f;
#pragma unroll
    for (int i = 0; i < 16; ++i) {
        const float v = src[i];
        s += v * v;
        const _Float16 h = (_Float16)(v * 1024.f);
        if (i < 8) h0[i] = h; else h1[i - 8] = h;
    }
    const int g = row >> 8, sidx = (row >> 4) & 15, m = row & 15, e = m & 7;
    const int j0 = (t & 15) * 2;                  // two 16B chunks per thread
    unsigned short* tile = chs + sidx * 16384 + g * 4096 + m * 256;
    *(half8*)(tile + (((j0    ) ^ e) << 3)) = h0;
    *(half8*)(tile + (((j0 + 1) ^ e) << 3)) = h1;
#pragma unroll
    for (int off = 1; off < 16; off <<= 1) s += __shfl_xor(s, off);
    if ((t & 15) == 0) sq[row] = s;
}

// ---- fused vq: grid 512 (2/CU), 256 thr = 4 waves (one per code group), M=64.
// Main loop is BARRIER-FREE: each wave stages and reads a private 8KB slice,
// synchronized only by its own counted s_waitcnt vmcnt(8) (m201 pattern).
__global__ __launch_bounds__(256, 2) void vq_kernel(
    const float* __restrict__ x, const float* __restrict__ cb,
    const unsigned short* __restrict__ chs, const float* __restrict__ sq,
    int* __restrict__ counts, float* __restrict__ loss_accum,
    float* __restrict__ out)
{
    __shared__ __align__(16) unsigned char Arena[65536]; // XL(32K) -> B dbuf(64K) -> Q(33K)
    __shared__ float mv[4][64];
    __shared__ int   mk[4][64];
    __shared__ float xsqL[64];
    __shared__ int   codeL[64];

    const int t = threadIdx.x;
    const int lane = t & 63;
    const int w = t >> 6;             // 0..3 = code group
    const int m = lane & 15;
    const int q = lane >> 4;
    const int kb = w << 8;
    const int bid = blockIdx.x;
    const int batch = bid >> 4;
    const int hwb = (bid & 15) << 6;  // 64 hw rows per block

    // ---- x staging: fp32 [c][hw] (coalesced) -> fp16 [hw:64][c:256] LDS.
    unsigned short* XL = (unsigned short*)Arena;
    {
        const float* xg = x + (size_t)batch * 262144 + hwb;
#pragma unroll
        for (int p = 0; p < 4; ++p) {
            const int id = p * 256 + t;
            const int c4 = id >> 4;       // 0..63 (c-group of 4)
            const int hw4 = id & 15;      // 0..15 (hw-group of 4)
            const float* s0 = xg + (size_t)(c4 * 4) * 1024 + hw4 * 4;
            const f32x4 v0 = *(const f32x4*)(s0);
            const f32x4 v1 = *(const f32x4*)(s0 + 1024);
            const f32x4 v2 = *(const f32x4*)(s0 + 2048);
            const f32x4 v3 = *(const f32x4*)(s0 + 3072);
#pragma unroll
            for (int j = 0; j < 4; ++j) {
                const int hw = hw4 * 4 + j;
                const int e = (((hw & 7) ^ ((hw >> 3) & 7)) << 1);
                half4v hv;
                hv[0] = (_Float16)v0[j];
                hv[1] = (_Float16)v1[j];
                hv[2] = (_Float16)v2[j];
                hv[3] = (_Float16)v3[j];
                *(half4v*)(XL + hw * 256 + ((c4 ^ e) << 2)) = hv;
            }
        }
    }
    __syncthreads();

    const char* chsB = (const char*)chs;
    char* bsB = (char*)Arena;
    const int so = w * 8192 + lane * 16;  // wave's linear slice of a 32KB stage

    // ||c||^2 for all 16 stages -> registers (loop must contain NO other vmem
    // so the counted vmcnt arithmetic stays exact; fully unrolled -> static idx)
    float sc2v[16];
#pragma unroll
    for (int s = 0; s < 16; ++s) sc2v[s] = sq[kb + s * 16 + m];

    // stage 0 -> buf1 (bytes 32768..65536: does NOT overlap XL); its latency
    // hides under the A-frag build; pre-loop barrier drains it.
    {
        const char* src = chsB + so;
        char* dst = bsB + 32768 + w * 8192;
#pragma unroll
        for (int i = 0; i < 8; ++i)
            __builtin_amdgcn_global_load_lds(
                (const __attribute__((address_space(1))) void*)(src + i * 1024),
                (__attribute__((address_space(3))) void*)(dst + i * 1024), 16, 0, 0);
    }

    // ---- A frags from LDS (conflict-free b128); fused ||x||^2 (fp16 path)
    half8 Ah[4][8];
#pragma unroll
    for (int f = 0; f < 4; ++f) {
        const int hw = f * 16 + m;
        const unsigned short* row = XL + hw * 256;
        const int e = (((hw & 7) ^ ((hw >> 3) & 7)) << 1);
        float xs = 0.f;
#pragma unroll
        for (int ks = 0; ks < 8; ++ks) {
            const half8 a = *(const half8*)(row + (((8 * ks + 2 * q) ^ e) << 2));
            Ah[f][ks] = a;
#pragma unroll
            for (int j = 0; j < 8; ++j) { const float fv = (float)a[j]; xs = fmaf(fv, fv, xs); }
        }
        xs += __shfl_xor(xs, 16);
        xs += __shfl_xor(xs, 32);
        if (w == 0 && q == 0) xsqL[hw] = xs;
    }
    __syncthreads();   // XL dead (all waves' frag reads done); arena = B dbuf
                       // (also drains stage-0 gloads + sq loads -> vmcnt == 0 here)

    float bestv[4][4];
    int   bestk[4][4];
#pragma unroll
    for (int f = 0; f < 4; ++f)
#pragma unroll
        for (int r = 0; r < 4; ++r) { bestv[f][r] = 3.4e38f; bestk[f][r] = 0; }

    const int rbase = w * 8192 + m * 512 + ((q ^ (m & 3)) << 4);
    const int eh = (m >> 2) & 1;

    // ---- BARRIER-FREE main loop: per-wave double-buffer, counted vmcnt.
    // iter s: [issue 8 gloads for s+1 into buf^1] -> vmcnt(8) (stage s's 8
    // oldest done) -> ds_read/MFMA on buf. Wave-private slices; no races.
#pragma unroll
    for (int s = 0; s < 16; ++s) {
        const int buf = (s + 1) & 1;  // stage0 lives in buf1
        if (s + 1 < 16) {
            const char* src = chsB + (s + 1) * 32768 + so;
            char* dst = bsB + ((buf ^ 1) * 32768) + w * 8192;
#pragma unroll
            for (int i = 0; i < 8; ++i)
                __builtin_amdgcn_global_load_lds(
                    (const __attribute__((address_space(1))) void*)(src + i * 1024),
                    (__attribute__((address_space(3))) void*)(dst + i * 1024), 16, 0, 0);
            asm volatile("s_waitcnt vmcnt(8)" ::: "memory");
        } else {
            asm volatile("s_waitcnt vmcnt(0)" ::: "memory");
        }
        __builtin_amdgcn_sched_barrier(0);   // rule 18: pin reads after the wait

        f32x4 a0 = {0.f,0.f,0.f,0.f}, a1 = {0.f,0.f,0.f,0.f};
        f32x4 a2 = {0.f,0.f,0.f,0.f}, a3 = {0.f,0.f,0.f,0.f};
        const char* bp = bsB + buf * 32768 + rbase;
        __builtin_amdgcn_s_setprio(1);
#pragma unroll
        for (int ks = 0; ks < 8; ++ks) {
            const half8 b = *(const half8*)(bp + ((ks ^ eh) << 6));
            a0 = __builtin_amdgcn_mfma_f32_16x16x32_f16(Ah[0][ks], b, a0, 0, 0, 0);
            a1 = __builtin_amdgcn_mfma_f32_16x16x32_f16(Ah[1][ks], b, a1, 0, 0, 0);
            a2 = __builtin_amdgcn_mfma_f32_16x16x32_f16(Ah[2][ks], b, a2, 0, 0, 0);
            a3 = __builtin_amdgcn_mfma_f32_16x16x32_f16(Ah[3][ks], b, a3, 0, 0, 0);
        }
        __builtin_amdgcn_s_setprio(0);
        const int code = kb + s * 16 + m;
        const float sc2 = sc2v[s];
#pragma unroll
        for (int f = 0; f < 4; ++f) {
            const f32x4 a = (f == 0) ? a0 : (f == 1) ? a1 : (f == 2) ? a2 : a3;
#pragma unroll
            for (int r = 0; r < 4; ++r) {
                const float d0v = fmaf(-0.001953125f, a[r], sc2);  // -2/1024 undoes B scale
                if (d0v < bestv[f][r]) { bestv[f][r] = d0v; bestk[f][r] = code; }
            }
        }
    }

    // per-row argmin across the 16 code-classes; tie -> lower k
#pragma unroll
    for (int f = 0; f < 4; ++f)
#pragma unroll
        for (int r = 0; r < 4; ++r) {
            float v = bestv[f][r];
            int   k = bestk[f][r];
#pragma unroll
            for (int d = 1; d < 16; d <<= 1) {
                const float ov = __shfl_xor(v, d);
                const int   ok = __shfl_xor(k, d);
                if (ov < v || (ov == v && ok < k)) { v = ov; k = ok; }
            }
            if (m == 0) {
                const int row = f * 16 + q * 4 + r;
                mv[w][row] = v;
                mk[w][row] = k;
            }
        }
    __syncthreads();

    // merge 4 code-groups (ascending g, strict < keeps lower code), hist + loss
    if (t < 64) {
        float v = mv[0][t]; int k = mk[0][t];
#pragma unroll
        for (int g2 = 1; g2 < 4; ++g2) {
            const float vg = mv[g2][t];
            const int   kg = mk[g2][t];
            if (vg < v) { v = vg; k = kg; }
        }
        codeL[t] = k;
        atomicAdd(&counts[k], 1);
        float lp = xsqL[t] + v;       // ||x - c||^2
#pragma unroll
        for (int off = 32; off > 0; off >>= 1) lp += __shfl_down(lp, off);
        if (t == 0) atomicAdd(loss_accum, lp);
    }
    __syncthreads();                  // codeL ready; loop's last B reads done

    // ---- fused gather: two 32-row halves through Q[32][257] (fp32, in arena)
    float* Q = (float*)Arena;
#pragma unroll
    for (int h = 0; h < 2; ++h) {
        {   // stage 32 cb rows
            const int r = t & 31, seg = t >> 5;   // 8 segments x 32 c
            const float* src = cb + (size_t)codeL[h * 32 + r] * 256 + seg * 32;
#pragma unroll
            for (int i = 0; i < 8; ++i)
                *(f32x4*)&Q[r * 257 + seg * 32 + i * 4] = *(const f32x4*)(src + i * 4);
        }
        __syncthreads();
        {   // transpose write: 128B-contiguous fp32 runs per c
            const int hw4 = (t & 7) * 4;
            const int c0 = t >> 3;                // 0..31
            float* dst = out + (size_t)batch * 262144 + hwb + h * 32 + hw4;
#pragma unroll
            for (int i = 0; i < 8; ++i) {
                const int c = c0 + i * 32;
                f32x4 v;
                v[0] = Q[(hw4 + 0) * 257 + c];
                v[1] = Q[(hw4 + 1) * 257 + c];
                v[2] = Q[(hw4 + 2) * 257 + c];
                v[3] = Q[(hw4 + 3) * 257 + c];
                *(f32x4*)(dst + (size_t)c * 1024) = v;
            }
        }
        if (h == 0) __syncthreads();  // before overwriting Q for half 1
    }
}

// ---- finalize: perplexity + loss scalar outputs (counts complete: kernel boundary)
__global__ __launch_bounds__(256) void finalize_kernel(
    const int* __restrict__ counts, const float* __restrict__ loss_accum,
    float* __restrict__ out)
{
    __shared__ float wsum[4];
    const int t = threadIdx.x;
    float s = 0.f;
#pragma unroll
    for (int mm = 0; mm < 4; ++mm) {
        const float p = (float)counts[t + 256 * mm] * (1.f / 32768.f);
        s += p * logf(p + 1e-10f);
    }
#pragma unroll
    for (int off = 32; off > 0; off >>= 1) s += __shfl_down(s, off);
    if ((t & 63) == 0) wsum[t >> 6] = s;
    __syncthreads();
    if (t == 0) {
        out[OUT_ELEMS]     = loss_accum[0] * (1.25f / 8388608.f);
        out[OUT_ELEMS + 1] = expf(-(wsum[0] + wsum[1] + wsum[2] + wsum[3]));
    }
}

extern "C" void kernel_launch(void* const* d_in, const int* in_sizes, int n_in,
                              void* d_out, int out_size, void* d_ws, size_t ws_size,
                              hipStream_t stream) {
    const float* x  = (const float*)d_in[0];
    const float* cb = (const float*)d_in[1];
    float* out = (float*)d_out;
    char* wsb = (char*)d_ws;
    int*            counts = (int*)(wsb + 0);
    float*          loss   = (float*)(wsb + 4096);
    float*          sq     = (float*)(wsb + 8192);
    unsigned short* chs    = (unsigned short*)(wsb + 16384);

    prep_kernel<<<64, 256, 0, stream>>>(cb, chs, sq, counts, loss);
    vq_kernel<<<512, 256, 0, stream>>>(x, cb, chs, sq, counts, loss, out);
    finalize_kernel<<<1, 256, 0, stream>>>(counts, loss, out);
}

// Round 5
// 139.097 us; speedup vs baseline: 1.0055x; 1.0055x over previous
//
#include <hip/hip_runtime.h>
#include <hip/hip_fp16.h>

typedef _Float16 half8 __attribute__((ext_vector_type(8)));
typedef _Float16 half4v __attribute__((ext_vector_type(4)));
typedef __attribute__((ext_vector_type(4))) float f32x4;

#define OUT_ELEMS 8388608

// ws layout (bytes):
// 0      counts int[1024]        (zeroed by prep block 0)
// 4096   loss   float            (zeroed by prep)
// 8192   sq     float[1024]
// 16384  chs    ushort[1024*256] (fp16 of 1024*cb, TILED+SWIZZLED, see below)
//
// chs layout (ushorts): [stage s:16][group g:4][chunk:512][8]
//   code = g*256 + s*16 + m; logical 16B chunk j (d = j*8, j=0..31) of code m
//   is stored at chunk position  m*32 + (j ^ (m&7))   (XOR swizzle).
// vq stages each 8KB wave-slice LINEARLY into LDS via global_load_lds
// (linear dest required) and reads B-frags with the same XOR -> conflict-free.

// ---- prep: zero accumulators + codebook -> fp16*1024 (tiled/swizzled) + ||c||^2 ----
__global__ __launch_bounds__(256) void prep_kernel(const float* __restrict__ cb,
        unsigned short* __restrict__ chs, float* __restrict__ sq,
        int* __restrict__ counts, float* __restrict__ loss) {
    const int t = threadIdx.x;
    if (blockIdx.x == 0) {
        ((int4*)counts)[t] = make_int4(0, 0, 0, 0);
        if (t == 0) *loss = 0.f;
    }
    const int row = blockIdx.x * 16 + (t >> 4);   // code index 0..1023
    const int d0 = (t & 15) * 16;
    const float* src = cb + row * 256 + d0;
    half8 h0, h1;
    float s = 0.f;
#pragma unroll
    for (int i = 0; i < 16; ++i) {
        const float v = src[i];
        s += v * v;
        const _Float16 h = (_Float16)(v * 1024.f);
        if (i < 8) h0[i] = h; else h1[i - 8] = h;
    }
    const int g = row >> 8, sidx = (row >> 4) & 15, m = row & 15, e = m & 7;
    const int j0 = (t & 15) * 2;                  // two 16B chunks per thread
    unsigned short* tile = chs + sidx * 16384 + g * 4096 + m * 256;
    *(half8*)(tile + (((j0    ) ^ e) << 3)) = h0;
    *(half8*)(tile + (((j0 + 1) ^ e) << 3)) = h1;
#pragma unroll
    for (int off = 1; off < 16; off <<= 1) s += __shfl_xor(s, off);
    if ((t & 15) == 0) sq[row] = s;
}

// ---- fused vq: grid 512 (2/CU), 256 thr = 4 waves (one per code group), M=64.
// Main loop is BARRIER-FREE: each wave stages and reads a private 8KB slice,
// synchronized only by its own counted s_waitcnt vmcnt(9): each iteration
// issues exactly 9 vmem ops (8 global_load_lds + 1 sq load), so vmcnt(9)
// drains precisely the previous iteration's ops. Loop stays ROLLED
// (unroll 2) -- R4's full unroll spilled ~160 regs (WRITE_SIZE 3x).
// x loads / out stores are non-temporal so chs+cb stay L2-resident.
__global__ __launch_bounds__(256, 2) void vq_kernel(
    const float* __restrict__ x, const float* __restrict__ cb,
    const unsigned short* __restrict__ chs, const float* __restrict__ sq,
    int* __restrict__ counts, float* __restrict__ loss_accum,
    float* __restrict__ out)
{
    __shared__ __align__(16) unsigned char Arena[65536]; // XL(32K) -> B dbuf(64K) -> Q(33K)
    __shared__ float mv[4][64];
    __shared__ int   mk[4][64];
    __shared__ float xsqL[64];
    __shared__ int   codeL[64];

    const int t = threadIdx.x;
    const int lane = t & 63;
    const int w = t >> 6;             // 0..3 = code group
    const int m = lane & 15;
    const int q = lane >> 4;
    const int kb = w << 8;
    const int bid = blockIdx.x;
    const int batch = bid >> 4;
    const int hwb = (bid & 15) << 6;  // 64 hw rows per block

    // ---- x staging: fp32 [c][hw] (coalesced, NT loads) -> fp16 [hw:64][c:256] LDS.
    unsigned short* XL = (unsigned short*)Arena;
    {
        const float* xg = x + (size_t)batch * 262144 + hwb;
#pragma unroll
        for (int p = 0; p < 4; ++p) {
            const int id = p * 256 + t;
            const int c4 = id >> 4;       // 0..63 (c-group of 4)
            const int hw4 = id & 15;      // 0..15 (hw-group of 4)
            const float* s0 = xg + (size_t)(c4 * 4) * 1024 + hw4 * 4;
            const f32x4 v0 = __builtin_nontemporal_load((const f32x4*)(s0));
            const f32x4 v1 = __builtin_nontemporal_load((const f32x4*)(s0 + 1024));
            const f32x4 v2 = __builtin_nontemporal_load((const f32x4*)(s0 + 2048));
            const f32x4 v3 = __builtin_nontemporal_load((const f32x4*)(s0 + 3072));
#pragma unroll
            for (int j = 0; j < 4; ++j) {
                const int hw = hw4 * 4 + j;
                const int e = (((hw & 7) ^ ((hw >> 3) & 7)) << 1);
                half4v hv;
                hv[0] = (_Float16)v0[j];
                hv[1] = (_Float16)v1[j];
                hv[2] = (_Float16)v2[j];
                hv[3] = (_Float16)v3[j];
                *(half4v*)(XL + hw * 256 + ((c4 ^ e) << 2)) = hv;
            }
        }
    }
    __syncthreads();

    const char* chsB = (const char*)chs;
    char* bsB = (char*)Arena;
    const int so = w * 8192 + lane * 16;  // wave's linear slice of a 32KB stage

    // stage 0 -> buf1 (bytes 32768..65536: does NOT overlap XL); its latency
    // hides under the A-frag build; the pre-loop barrier drains it (vmcnt=0
    // at loop entry -- required for the counted-vmcnt arithmetic).
    {
        const char* src = chsB + so;
        char* dst = bsB + 32768 + w * 8192;
#pragma unroll
        for (int i = 0; i < 8; ++i)
            __builtin_amdgcn_global_load_lds(
                (const __attribute__((address_space(1))) void*)(src + i * 1024),
                (__attribute__((address_space(3))) void*)(dst + i * 1024), 16, 0, 0);
    }
    float sc2 = sq[kb + m];           // stage-0 ||c||^2

    // ---- A frags from LDS (conflict-free b128); fused ||x||^2 (fp16 path)
    half8 Ah[4][8];
#pragma unroll
    for (int f = 0; f < 4; ++f) {
        const int hw = f * 16 + m;
        const unsigned short* row = XL + hw * 256;
        const int e = (((hw & 7) ^ ((hw >> 3) & 7)) << 1);
        float xs = 0.f;
#pragma unroll
        for (int ks = 0; ks < 8; ++ks) {
            const half8 a = *(const half8*)(row + (((8 * ks + 2 * q) ^ e) << 2));
            Ah[f][ks] = a;
#pragma unroll
            for (int j = 0; j < 8; ++j) { const float fv = (float)a[j]; xs = fmaf(fv, fv, xs); }
        }
        xs += __shfl_xor(xs, 16);
        xs += __shfl_xor(xs, 32);
        if (w == 0 && q == 0) xsqL[hw] = xs;
    }
    __syncthreads();   // XL dead (all waves' frag reads done); arena = B dbuf.
                       // Barrier drains vmcnt -> 0 (stage-0 + sc2 complete).

    float bestv[4][4];
    int   bestk[4][4];
#pragma unroll
    for (int f = 0; f < 4; ++f)
#pragma unroll
        for (int r = 0; r < 4; ++r) { bestv[f][r] = 3.4e38f; bestk[f][r] = 0; }

    const int rbase = w * 8192 + m * 512 + ((q ^ (m & 3)) << 4);
    const int eh = (m >> 2) & 1;

#define VQ_COMPUTE(S, BUF)                                                      \
    {                                                                           \
        f32x4 a0 = {0.f,0.f,0.f,0.f}, a1 = {0.f,0.f,0.f,0.f};                   \
        f32x4 a2 = {0.f,0.f,0.f,0.f}, a3 = {0.f,0.f,0.f,0.f};                   \
        const char* bp = bsB + (BUF) * 32768 + rbase;                           \
        __builtin_amdgcn_s_setprio(1);                                          \
        _Pragma("unroll")                                                       \
        for (int ks = 0; ks < 8; ++ks) {                                        \
            const half8 b = *(const half8*)(bp + ((ks ^ eh) << 6));             \
            a0 = __builtin_amdgcn_mfma_f32_16x16x32_f16(Ah[0][ks], b, a0,0,0,0);\
            a1 = __builtin_amdgcn_mfma_f32_16x16x32_f16(Ah[1][ks], b, a1,0,0,0);\
            a2 = __builtin_amdgcn_mfma_f32_16x16x32_f16(Ah[2][ks], b, a2,0,0,0);\
            a3 = __builtin_amdgcn_mfma_f32_16x16x32_f16(Ah[3][ks], b, a3,0,0,0);\
        }                                                                       \
        __builtin_amdgcn_s_setprio(0);                                          \
        const int code = kb + (S) * 16 + m;                                     \
        _Pragma("unroll")                                                       \
        for (int f = 0; f < 4; ++f) {                                           \
            const f32x4 a = (f==0)?a0:(f==1)?a1:(f==2)?a2:a3;                   \
            _Pragma("unroll")                                                   \
            for (int r = 0; r < 4; ++r) {                                       \
                const float d0v = fmaf(-0.001953125f, a[r], sc2);               \
                if (d0v < bestv[f][r]) { bestv[f][r] = d0v; bestk[f][r] = code; }\
            }                                                                   \
        }                                                                       \
    }

    // ---- BARRIER-FREE main loop (stages 0..14; stage 15 peeled).
#pragma unroll 2
    for (int s = 0; s < 15; ++s) {
        const int pbuf = s & 1;       // prefetch dest for stage s+1 (stage0=buf1)
        {
            const char* src = chsB + (s + 1) * 32768 + so;
            char* dst = bsB + pbuf * 32768 + w * 8192;
#pragma unroll
            for (int i = 0; i < 8; ++i)
                __builtin_amdgcn_global_load_lds(
                    (const __attribute__((address_space(1))) void*)(src + i * 1024),
                    (__attribute__((address_space(3))) void*)(dst + i * 1024), 16, 0, 0);
        }
        const float sq_next = sq[kb + (s + 1) * 16 + m];   // vmem #9 this iter
        asm volatile("s_waitcnt vmcnt(9)" ::: "memory");   // drain prev iter's 9
        __builtin_amdgcn_sched_barrier(0);                 // pin reads after wait
        VQ_COMPUTE(s, pbuf ^ 1)
        sc2 = sq_next;
    }
    asm volatile("s_waitcnt vmcnt(0)" ::: "memory");
    __builtin_amdgcn_sched_barrier(0);
    VQ_COMPUTE(15, 0)
#undef VQ_COMPUTE

    // per-row argmin across the 16 code-classes; tie -> lower k
#pragma unroll
    for (int f = 0; f < 4; ++f)
#pragma unroll
        for (int r = 0; r < 4; ++r) {
            float v = bestv[f][r];
            int   k = bestk[f][r];
#pragma unroll
            for (int d = 1; d < 16; d <<= 1) {
                const float ov = __shfl_xor(v, d);
                const int   ok = __shfl_xor(k, d);
                if (ov < v || (ov == v && ok < k)) { v = ov; k = ok; }
            }
            if (m == 0) {
                const int row = f * 16 + q * 4 + r;
                mv[w][row] = v;
                mk[w][row] = k;
            }
        }
    __syncthreads();

    // merge 4 code-groups (ascending g, strict < keeps lower code), hist + loss
    if (t < 64) {
        float v = mv[0][t]; int k = mk[0][t];
#pragma unroll
        for (int g2 = 1; g2 < 4; ++g2) {
            const float vg = mv[g2][t];
            const int   kg = mk[g2][t];
            if (vg < v) { v = vg; k = kg; }
        }
        codeL[t] = k;
        atomicAdd(&counts[k], 1);
        float lp = xsqL[t] + v;       // ||x - c||^2
#pragma unroll
        for (int off = 32; off > 0; off >>= 1) lp += __shfl_down(lp, off);
        if (t == 0) atomicAdd(loss_accum, lp);
    }
    __syncthreads();                  // codeL ready; loop's last B reads done

    // ---- fused gather: two 32-row halves through Q[32][257] (fp32, in arena)
    float* Q = (float*)Arena;
#pragma unroll
    for (int h = 0; h < 2; ++h) {
        {   // stage 32 cb rows (cb stays cacheable: reused across all blocks)
            const int r = t & 31, seg = t >> 5;   // 8 segments x 32 c
            const float* src = cb + (size_t)codeL[h * 32 + r] * 256 + seg * 32;
#pragma unroll
            for (int i = 0; i < 8; ++i)
                *(f32x4*)&Q[r * 257 + seg * 32 + i * 4] = *(const f32x4*)(src + i * 4);
        }
        __syncthreads();
        {   // transpose write: 128B-contiguous fp32 runs per c (NT stores)
            const int hw4 = (t & 7) * 4;
            const int c0 = t >> 3;                // 0..31
            float* dst = out + (size_t)batch * 262144 + hwb + h * 32 + hw4;
#pragma unroll
            for (int i = 0; i < 8; ++i) {
                const int c = c0 + i * 32;
                f32x4 v;
                v[0] = Q[(hw4 + 0) * 257 + c];
                v[1] = Q[(hw4 + 1) * 257 + c];
                v[2] = Q[(hw4 + 2) * 257 + c];
                v[3] = Q[(hw4 + 3) * 257 + c];
                __builtin_nontemporal_store(v, (f32x4*)(dst + (size_t)c * 1024));
            }
        }
        if (h == 0) __syncthreads();  // before overwriting Q for half 1
    }
}

// ---- finalize: perplexity + loss scalar outputs (counts complete: kernel boundary)
__global__ __launch_bounds__(256) void finalize_kernel(
    const int* __restrict__ counts, const float* __restrict__ loss_accum,
    float* __restrict__ out)
{
    __shared__ float wsum[4];
    const int t = threadIdx.x;
    float s = 0.f;
#pragma unroll
    for (int mm = 0; mm < 4; ++mm) {
        const float p = (float)counts[t + 256 * mm] * (1.f / 32768.f);
        s += p * logf(p + 1e-10f);
    }
#pragma unroll
    for (int off = 32; off > 0; off >>= 1) s += __shfl_down(s, off);
    if ((t & 63) == 0) wsum[t >> 6] = s;
    __syncthreads();
    if (t == 0) {
        out[OUT_ELEMS]     = loss_accum[0] * (1.25f / 8388608.f);
        out[OUT_ELEMS + 1] = expf(-(wsum[0] + wsum[1] + wsum[2] + wsum[3]));
    }
}

extern "C" void kernel_launch(void* const* d_in, const int* in_sizes, int n_in,
                              void* d_out, int out_size, void* d_ws, size_t ws_size,
                              hipStream_t stream) {
    const float* x  = (const float*)d_in[0];
    const float* cb = (const float*)d_in[1];
    float* out = (float*)d_out;
    char* wsb = (char*)d_ws;
    int*            counts = (int*)(wsb + 0);
    float*          loss   = (float*)(wsb + 4096);
    float*          sq     = (float*)(wsb + 8192);
    unsigned short* chs    = (unsigned short*)(wsb + 16384);

    prep_kernel<<<64, 256, 0, stream>>>(cb, chs, sq, counts, loss);
    vq_kernel<<<512, 256, 0, stream>>>(x, cb, chs, sq, counts, loss, out);
    finalize_kernel<<<1, 256, 0, stream>>>(counts, loss, out);
}

// Round 7
// 124.783 us; speedup vs baseline: 1.1208x; 1.1147x over previous
//
#include <hip/hip_runtime.h>
#include <hip/hip_fp16.h>

typedef _Float16 half8 __attribute__((ext_vector_type(8)));
typedef _Float16 half4v __attribute__((ext_vector_type(4)));
typedef __attribute__((ext_vector_type(4))) float f32x4;

#define OUT_ELEMS 8388608

// ws layout (bytes):
// 0      counts int[1024]        (zeroed by prep block 0)
// 4096   loss   float            (zeroed by prep)
// 8192   sq     float[1024]
// 16384  chs    ushort[1024*256] (fp16 of 1024*cb, ROW-MAJOR — swizzle applied
//                                 at vq's per-lane ds_write, not in memory)

// ---- prep: zero accumulators + codebook -> fp16*1024 + ||c||^2 ----
__global__ __launch_bounds__(256) void prep_kernel(const float* __restrict__ cb,
        unsigned short* __restrict__ chs, float* __restrict__ sq,
        int* __restrict__ counts, float* __restrict__ loss) {
    const int t = threadIdx.x;
    if (blockIdx.x == 0) {
        ((int4*)counts)[t] = make_int4(0, 0, 0, 0);
        if (t == 0) *loss = 0.f;
    }
    const int row = blockIdx.x * 16 + (t >> 4);   // code index 0..1023
    const int d0 = (t & 15) * 16;
    const float* src = cb + row * 256 + d0;
    half8 h0, h1;
    float s = 0.f;
#pragma unroll
    for (int i = 0; i < 16; ++i) {
        const float v = src[i];
        s += v * v;
        const _Float16 h = (_Float16)(v * 1024.f);
        if (i < 8) h0[i] = h; else h1[i - 8] = h;
    }
    *(half8*)(chs + row * 256 + d0)     = h0;
    *(half8*)(chs + row * 256 + d0 + 8) = h1;
#pragma unroll
    for (int off = 1; off < 16; off <<= 1) s += __shfl_xor(s, off);
    if ((t & 15) == 0) sq[row] = s;
}

// ---- fused vq: grid 256 (1/CU), 512 thr = 8 waves = 4 code-groups x 2 row-groups.
// M=128 rows/block, 1024 codes in 16 stages of 64 codes (16/code-group).
// Loop = R0's verified T14 shape: reg-prefetch BEFORE barrier, ds_write AFTER
// compute. NO inline asm / sched_barrier / setprio (R4/R5: those spilled Ah).
__global__ __launch_bounds__(512, 2) void vq_kernel(
    const float* __restrict__ x, const float* __restrict__ cb,
    const unsigned short* __restrict__ chs, const float* __restrict__ sq,
    int* __restrict__ counts, float* __restrict__ loss_accum,
    float* __restrict__ out)
{
    __shared__ __align__(16) unsigned char Arena[65536]; // XL(64K) -> B dbuf [2][32K] -> Q(33K)
    __shared__ float mv[4][128];
    __shared__ int   mk[4][128];
    __shared__ float xsqL[128];
    __shared__ int   codeL[128];
    __shared__ float wsum[2];

    const int t = threadIdx.x;
    const int lane = t & 63;
    const int w  = t >> 6;
    const int wg = w >> 1;            // code group 0..3 (256 codes each)
    const int wl = w & 1;             // row group 0..1 (64 rows each)
    const int m = lane & 15;
    const int q = lane >> 4;
    const int kb = wg << 8;
    const int rowb = wl << 6;
    const int bid = blockIdx.x;
    const int batch = bid >> 3;
    const int hwb = (bid & 7) << 7;   // 128 hw rows per block

    // stage-0 B prefetch issued FIRST (hides chs first-touch under x staging):
    // thread stages code slot cs = t>>3 (g = cs>>4, mm = cs&15), 64B = 4x16B chunks.
    const int cs = t >> 3, sg = cs >> 4, sm = cs & 15;
    const int sj0 = (t & 7) * 4;      // first 16B-chunk index (of 32 per code row)
    const unsigned short* srow = chs + ((sg << 8) + sm) * 256 + sj0 * 8;
    half8 n0, n1, n2, n3;
    n0 = *(const half8*)(srow);
    n1 = *(const half8*)(srow + 8);
    n2 = *(const half8*)(srow + 16);
    n3 = *(const half8*)(srow + 24);
    float sc2 = sq[kb + m];           // stage-0 ||c||^2

    // ---- x staging: fp32 [c][hw] (coalesced) -> fp16 [hw:128][c:256] LDS, swizzled
    // 8B-group swizzle e(hw) = ((hw&7) ^ ((hw>>3)&7)) << 1 (even keeps 16B pairs).
    unsigned short* XL = (unsigned short*)Arena;
    {
        const float* xg = x + (size_t)batch * 262144 + hwb;
#pragma unroll
        for (int p = 0; p < 4; ++p) {
            const int id = p * 512 + t;
            const int c4 = id >> 5;       // 0..63 (c-group of 4)
            const int hw4 = id & 31;      // 0..31 (hw-group of 4)
            const float* s0 = xg + (size_t)(c4 * 4) * 1024 + hw4 * 4;
            const f32x4 v0 = *(const f32x4*)(s0);
            const f32x4 v1 = *(const f32x4*)(s0 + 1024);
            const f32x4 v2 = *(const f32x4*)(s0 + 2048);
            const f32x4 v3 = *(const f32x4*)(s0 + 3072);
#pragma unroll
            for (int j = 0; j < 4; ++j) {
                const int hw = hw4 * 4 + j;
                const int e = (((hw & 7) ^ ((hw >> 3) & 7)) << 1);
                half4v hv;
                hv[0] = (_Float16)v0[j];
                hv[1] = (_Float16)v1[j];
                hv[2] = (_Float16)v2[j];
                hv[3] = (_Float16)v3[j];
                *(half4v*)(XL + hw * 256 + ((c4 ^ e) << 2)) = hv;
            }
        }
    }
    __syncthreads();

    // ---- A frags from LDS (conflict-free b128); fused ||x||^2 (fp16 path)
    half8 Ah[4][8];
#pragma unroll
    for (int f = 0; f < 4; ++f) {
        const int hw = rowb + f * 16 + m;
        const unsigned short* row = XL + hw * 256;
        const int e = (((hw & 7) ^ ((hw >> 3) & 7)) << 1);
        float xs = 0.f;
#pragma unroll
        for (int ks = 0; ks < 8; ++ks) {
            const half8 a = *(const half8*)(row + (((8 * ks + 2 * q) ^ e) << 2));
            Ah[f][ks] = a;
#pragma unroll
            for (int j = 0; j < 8; ++j) { const float fv = (float)a[j]; xs = fmaf(fv, fv, xs); }
        }
        xs += __shfl_xor(xs, 16);
        xs += __shfl_xor(xs, 32);
        if (wg == 0 && q == 0) xsqL[hw] = xs;
    }
    __syncthreads();   // XL dead (all waves' frag reads done); arena = B dbuf

    // B dbuf: [buf:2][code slot g*16+mm : 64][chunk j:32 swizzled j^(mm&7)][8 hw]
    unsigned short* Bs = (unsigned short*)Arena;
    {   // stage-0 write into buf0 (visible to all at the loop's first barrier)
        unsigned short* wb = Bs + cs * 256;
        *(half8*)(wb + (((sj0 + 0) ^ (sm & 7)) << 3)) = n0;
        *(half8*)(wb + (((sj0 + 1) ^ (sm & 7)) << 3)) = n1;
        *(half8*)(wb + (((sj0 + 2) ^ (sm & 7)) << 3)) = n2;
        *(half8*)(wb + (((sj0 + 3) ^ (sm & 7)) << 3)) = n3;
    }

    float bestv[4][4];
    int   bestk[4][4];
#pragma unroll
    for (int f = 0; f < 4; ++f)
#pragma unroll
        for (int r = 0; r < 4; ++r) { bestv[f][r] = 3.4e38f; bestk[f][r] = 0; }

    const unsigned short* brow = Bs + (wg * 16 + m) * 256;  // buf0 base, this wave
    const int eswz = m & 7;

    for (int s = 0; s < 16; ++s) {
        const int buf = s & 1;
        float sqn = 0.f;
        if (s + 1 < 16) {             // T14: prefetch s+1 to REGS before barrier
            const unsigned short* sp = srow + (s + 1) * 4096;
            n0 = *(const half8*)(sp);
            n1 = *(const half8*)(sp + 8);
            n2 = *(const half8*)(sp + 16);
            n3 = *(const half8*)(sp + 24);
            sqn = sq[kb + (s + 1) * 16 + m];
        }
        __syncthreads();              // buf's ds_writes (end of iter s-1) visible
        f32x4 a0 = {0.f,0.f,0.f,0.f}, a1 = {0.f,0.f,0.f,0.f};
        f32x4 a2 = {0.f,0.f,0.f,0.f}, a3 = {0.f,0.f,0.f,0.f};
        const unsigned short* bp = brow + buf * 16384;
#pragma unroll
        for (int ks = 0; ks < 8; ++ks) {
            const half8 b = *(const half8*)(bp + (((ks * 4 + q) ^ eswz) << 3));
            a0 = __builtin_amdgcn_mfma_f32_16x16x32_f16(Ah[0][ks], b, a0, 0, 0, 0);
            a1 = __builtin_amdgcn_mfma_f32_16x16x32_f16(Ah[1][ks], b, a1, 0, 0, 0);
            a2 = __builtin_amdgcn_mfma_f32_16x16x32_f16(Ah[2][ks], b, a2, 0, 0, 0);
            a3 = __builtin_amdgcn_mfma_f32_16x16x32_f16(Ah[3][ks], b, a3, 0, 0, 0);
        }
        const int code = kb + s * 16 + m;
#pragma unroll
        for (int f = 0; f < 4; ++f) {
            const f32x4 a = (f == 0) ? a0 : (f == 1) ? a1 : (f == 2) ? a2 : a3;
#pragma unroll
            for (int r = 0; r < 4; ++r) {
                const float d0v = fmaf(-0.001953125f, a[r], sc2);  // -2/1024 undoes B scale
                if (d0v < bestv[f][r]) { bestv[f][r] = d0v; bestk[f][r] = code; }
            }
        }
        if (s + 1 < 16) {             // write prefetched tile; safe: all waves
            unsigned short* wb = Bs + (buf ^ 1) * 16384 + cs * 256;  // passed this
            *(half8*)(wb + (((sj0 + 0) ^ (sm & 7)) << 3)) = n0;      // stage's barrier
            *(half8*)(wb + (((sj0 + 1) ^ (sm & 7)) << 3)) = n1;
            *(half8*)(wb + (((sj0 + 2) ^ (sm & 7)) << 3)) = n2;
            *(half8*)(wb + (((sj0 + 3) ^ (sm & 7)) << 3)) = n3;
            sc2 = sqn;
        }
    }

    // per-row argmin across the 16 code-classes; tie -> lower k
#pragma unroll
    for (int f = 0; f < 4; ++f)
#pragma unroll
        for (int r = 0; r < 4; ++r) {
            float v = bestv[f][r];
            int   k = bestk[f][r];
#pragma unroll
            for (int d = 1; d < 16; d <<= 1) {
                const float ov = __shfl_xor(v, d);
                const int   ok = __shfl_xor(k, d);
                if (ov < v || (ov == v && ok < k)) { v = ov; k = ok; }
            }
            if (m == 0) {
                const int row = rowb + f * 16 + q * 4 + r;
                mv[wg][row] = v;
                mk[wg][row] = k;
            }
        }
    __syncthreads();

    // merge 4 code-groups (ascending g, strict < keeps lower code), hist + loss
    if (t < 128) {
        float v = mv[0][t]; int k = mk[0][t];
#pragma unroll
        for (int g2 = 1; g2 < 4; ++g2) {
            const float vg = mv[g2][t];
            const int   kg = mk[g2][t];
            if (vg < v) { v = vg; k = kg; }
        }
        codeL[t] = k;
        atomicAdd(&counts[k], 1);
        float lp = xsqL[t] + v;       // ||x - c||^2
#pragma unroll
        for (int off = 32; off > 0; off >>= 1) lp += __shfl_down(lp, off);
        if ((t & 63) == 0) wsum[t >> 6] = lp;
    }
    __syncthreads();                  // codeL ready; loop's last B reads done
    if (t == 0) atomicAdd(loss_accum, wsum[0] + wsum[1]);

    // ---- fused gather: four 32-row quarters through Q[32][257] (fp32, in arena)
    float* Q = (float*)Arena;
#pragma unroll
    for (int h = 0; h < 4; ++h) {
        {   // stage 32 cb rows (cb L2-hot: reused across all blocks)
            const int r = t & 31, seg = t >> 5;   // 16 segments x 16 c
            const float* src = cb + (size_t)codeL[h * 32 + r] * 256 + seg * 16;
#pragma unroll
            for (int i = 0; i < 4; ++i)
                *(f32x4*)&Q[r * 257 + seg * 16 + i * 4] = *(const f32x4*)(src + i * 4);
        }
        __syncthreads();
        {   // transpose write: 128B-contiguous fp32 runs per c
            const int hw4 = (t & 7) * 4;
            const int c0 = t >> 3;                // 0..63
            float* dst = out + (size_t)batch * 262144 + hwb + h * 32 + hw4;
#pragma unroll
            for (int i = 0; i < 4; ++i) {
                const int c = c0 + i * 64;
                f32x4 v;
                v[0] = Q[(hw4 + 0) * 257 + c];
                v[1] = Q[(hw4 + 1) * 257 + c];
                v[2] = Q[(hw4 + 2) * 257 + c];
                v[3] = Q[(hw4 + 3) * 257 + c];
                *(f32x4*)(dst + (size_t)c * 1024) = v;
            }
        }
        if (h < 3) __syncthreads();   // before overwriting Q for next quarter
    }
}

// ---- finalize: perplexity + loss scalar outputs (counts complete: kernel boundary)
__global__ __launch_bounds__(256) void finalize_kernel(
    const int* __restrict__ counts, const float* __restrict__ loss_accum,
    float* __restrict__ out)
{
    __shared__ float wsum[4];
    const int t = threadIdx.x;
    float s = 0.f;
#pragma unroll
    for (int mm = 0; mm < 4; ++mm) {
        const float p = (float)counts[t + 256 * mm] * (1.f / 32768.f);
        s += p * logf(p + 1e-10f);
    }
#pragma unroll
    for (int off = 32; off > 0; off >>= 1) s += __shfl_down(s, off);
    if ((t & 63) == 0) wsum[t >> 6] = s;
    __syncthreads();
    if (t == 0) {
        out[OUT_ELEMS]     = loss_accum[0] * (1.25f / 8388608.f);
        out[OUT_ELEMS + 1] = expf(-(wsum[0] + wsum[1] + wsum[2] + wsum[3]));
    }
}

extern "C" void kernel_launch(void* const* d_in, const int* in_sizes, int n_in,
                              void* d_out, int out_size, void* d_ws, size_t ws_size,
                              hipStream_t stream) {
    const float* x  = (const float*)d_in[0];
    const float* cb = (const float*)d_in[1];
    float* out = (float*)d_out;
    char* wsb = (char*)d_ws;
    int*            counts = (int*)(wsb + 0);
    float*          loss   = (float*)(wsb + 4096);
    float*          sq     = (float*)(wsb + 8192);
    unsigned short* chs    = (unsigned short*)(wsb + 16384);

    prep_kernel<<<64, 256, 0, stream>>>(cb, chs, sq, counts, loss);
    vq_kernel<<<256, 512, 0, stream>>>(x, cb, chs, sq, counts, loss, out);
    finalize_kernel<<<1, 256, 0, stream>>>(counts, loss, out);
}